// Round 6
// baseline (1296.145 us; speedup 1.0000x reference)
//
#include <hip/hip_runtime.h>
#include <math.h>

#define S_N 3000
#define NCOLS 30000
#define SCHUNK 8       // one chunk per XCD -> K chunk L2-resident
#define KTILES 938     // ceil(30000/32)
#define TPC 118        // tiles per chunk (8*118 = 944 >= 938)
#define PST7 7         // P row stride (floats): odd -> conflict-free

typedef __bf16 v8bf __attribute__((ext_vector_type(8)));
typedef float v16f __attribute__((ext_vector_type(16)));
typedef float v4f __attribute__((ext_vector_type(4)));

__device__ __forceinline__ float sigm(float x) { return 1.0f / (1.0f + expf(-x)); }

__device__ __forceinline__ bool bet(float av, int ai, float bv, int bi) {
  return (av > bv) || (av == bv && ai < bi);
}

// streaming insert (candidates ascending by index): strict > == lax.top_k tie rule
template <int M>
__device__ __forceinline__ void insS(float (&v)[M], int (&ix)[M], float nv, int ni) {
  if (!(nv > v[M - 1])) return;
  bool b[M];
#pragma unroll
  for (int q = 0; q < M; q++) b[q] = nv > v[q];
#pragma unroll
  for (int q = M - 1; q > 0; q--) {
    v[q]  = b[q] ? (b[q - 1] ? v[q - 1] : nv) : v[q];
    ix[q] = b[q] ? (b[q - 1] ? ix[q - 1] : ni) : ix[q];
  }
  if (b[0]) { v[0] = nv; ix[0] = ni; }
}

// full comparator insert (value desc, index asc) for arbitrary-order merges
template <int M>
__device__ __forceinline__ void insF(float (&v)[M], int (&ix)[M], float nv, int ni) {
  if (!bet(nv, ni, v[M - 1], ix[M - 1])) return;
  bool b[M];
#pragma unroll
  for (int q = 0; q < M; q++) b[q] = bet(nv, ni, v[q], ix[q]);
#pragma unroll
  for (int q = M - 1; q > 0; q--) {
    v[q]  = b[q] ? (b[q - 1] ? v[q - 1] : nv) : v[q];
    ix[q] = b[q] ? (b[q - 1] ? ix[q - 1] : ni) : ix[q];
  }
  if (b[0]) { v[0] = nv; ix[0] = ni; }
}

__device__ __forceinline__ unsigned short f2bf_rne(float f) {
  unsigned int u = __float_as_uint(f);
  unsigned int r = (u + 0x7fffu + ((u >> 16) & 1u)) >> 16;
  return (unsigned short)r;
}
__device__ __forceinline__ float bf2f(unsigned short h) {
  return __uint_as_float(((unsigned int)h) << 16);
}

// ---------------------------------------------------------------------------
// Kernel 0: Whh third-split (ll) in fragment order, streamed by lstm per t.
// idx = frag*512 + lane*8 + j; frag = w*8 + tau*2 + s' (w = kh*8+g8, 0..15).
// (unchanged -- the 8-wave lstm indexes it with base = g8*4096 [+32768 for
// kh=1], same element placement.)
// ---------------------------------------------------------------------------
__global__ __launch_bounds__(256) void cvt_wll(
    const float* __restrict__ Whh, unsigned short* __restrict__ Wllf)
{
  int idx = blockIdx.x * 256 + threadIdx.x;
  if (idx >= 128 * 512) return;
  int f = idx >> 9;
  int lane = (idx >> 3) & 63;
  int j = idx & 7;
  int w = f >> 3, tau = (f >> 1) & 3, s = f & 1;
  int kh = w >> 3, g8 = w & 7;
  int gate = g8 * 64 + tau * 16 + (lane & 15);
  int k = kh * 64 + s * 32 + (lane >> 4) * 8 + j;
  float x = Whh[gate * 128 + k];
  unsigned short hi = f2bf_rne(x);
  float r1 = x - bf2f(hi);
  unsigned short lo = f2bf_rne(r1);
  float r2 = r1 - bf2f(lo);
  Wllf[idx] = f2bf_rne(r2);
}

// ---------------------------------------------------------------------------
// Kernel 1: LSTM via MFMA (bf16 x3 splits, 6 MFMAs/product, fp32-noise err).
// R15: STRUCTURAL change -- 2 blocks/CU. R13/R14 post-mortems: bank conflicts
// are ~5% of the t-step (640/12400 cyc); MfmaUtil 21% + VALUBusy 35% leaves
// >45% dual-idle = barrier/latency stalls of a single 16-wave lockstep block.
// Split 250x1024 (12 seq) -> 500x512 (6 seq): LDS 62KB/block -> 2 blocks
// co-resident per CU with INDEPENDENT barriers -> block A phase-1 (MFMA)
// overlaps block B phase-2 (VALU/transcendental).
// Each wave (wv=g8, 0..7) now computes full K=128 (s=0..3 subtiles; resident
// whi/wlo 32 v8bf -> AGPRs). BIT-IDENTICAL numerics: two accumulators keep
// the old kh=0 (s0,1) / kh=1 (s2,3) partial-sum chains in the old MFMA
// order; phase 2 adds P_lo+P_hi in the old order. P = 2x[512][7] (odd
// stride, store/read lane patterns verified conflict-free). Asp row-perm
// (R13) kept; WB2 float2 (R11 form); Xb8 broadcast reads (m,t uniform).
// ---------------------------------------------------------------------------
__global__ __launch_bounds__(512, 4) void lstm_kernel(
    const float* __restrict__ Xs, const float* __restrict__ Wih,
    const float* __restrict__ Whh, const float* __restrict__ bih,
    const float* __restrict__ bhh, const unsigned short* __restrict__ Wllf,
    float* __restrict__ H10)
{
  __shared__ float P[2 * 512 * PST7];                 // 28.7 KB
  __shared__ __align__(16) __bf16 Asp[3][4][65][8];   // 12.2 KB, ks-padded
  __shared__ __align__(16) float Xb8[6 * 41 * 8];     // 7.9 KB, padded rows
  __shared__ float2 WB2[14][128];                     // 14.3 KB packed wih+bias

  const int tid = threadIdx.x;
  const int s0 = blockIdx.x * 6;
  const int lane = tid & 63;
  const int g8 = tid >> 6;             // wave = g8 group, 0..7
  const int l15 = lane & 15, lq = lane >> 4;

  // Xb8[(m*41 + t)*8 + f] = x[s0+m][t][f] (f<6; pad 0)
  for (int i = tid; i < 6 * 40 * 8; i += 512) {
    int m = i / 320, r = i - m * 320, t = r >> 3, f = r & 7;
    Xb8[(m * 41 + t) * 8 + f] =
        (f < 6) ? Xs[(size_t)(s0 + m) * 240 + t * 6 + f] : 0.0f;
  }
  for (int i = tid; i < 3 * 4 * 65 * 8; i += 512)
    ((unsigned short*)Asp)[i] = 0;   // h0 = 0 (and zero pad/unused rows)
  for (int i = tid; i < 14 * 128; i += 512) {
    int q = i >> 7, n = i & 127;
    float vv[2];
#pragma unroll
    for (int e = 0; e < 2; e++) {
      int r = 2 * q + e;
      if (r < 24) {
        int gate = n + (r / 6) * 128;
        vv[e] = Wih[gate * 6 + r % 6];
      } else {
        int gate = n + (r - 24) * 128;
        vv[e] = bih[gate] + bhh[gate];
      }
    }
    WB2[q][n] = make_float2(vv[0], vv[1]);
  }

  // resident weight fragments hi/lo for ALL of K: s = kh*2+s' in 0..3
  // B-layout (n=l15 -> gate, quad -> k+8*lq). 32 v8bf = 128 regs (AGPR).
  v8bf whi[4][4], wlo[4][4];
#pragma unroll
  for (int tau = 0; tau < 4; tau++)
#pragma unroll
    for (int s = 0; s < 4; s++) {
      int gate = g8 * 64 + tau * 16 + l15;
      int k0 = (s >> 1) * 64 + (s & 1) * 32 + lq * 8;
      const float* wp = Whh + gate * 128 + k0;
      v8bf h8, l8;
#pragma unroll
      for (int j = 0; j < 8; j++) {
        float x = wp[j];
        __bf16 bh_ = (__bf16)x;
        float r1 = x - (float)bh_;
        __bf16 bl_ = (__bf16)r1;
        h8[j] = bh_;
        l8[j] = bl_;
      }
      whi[tau][s] = h8;
      wlo[tau][s] = l8;
    }

  // wll stream base: frag = (kh*8+g8)*8 + tau*2 + s'; kh adds 64 frags.
  const unsigned short* wllbase = Wllf + (size_t)g8 * 4096 + lane * 8;

  float c0 = 0.0f, c1 = 0.0f;
  // phase-2 assignment (R11-style): n = tid&127 (lane-varying), m wave-pair
  // uniform -> P reads 17..; here 7*lane bijective mod 32 -> conflict-free.
  const int p2n = tid & 127;
  const int mq = tid >> 7;             // 0..3
  // read row for fragment row `lane`: inverse of store row-permutation
  const int rdrow = (lane & 48) | ((lane + 2 * (lane >> 4)) & 15);

  __syncthreads();

#pragma unroll 1
  for (int t = 0; t < 40; t++) {
    // ---- phase 1: recurrent GEMM on MFMA, full K per wave ----
    v8bf ah[4], al[4], a3[4];
#pragma unroll
    for (int s = 0; s < 4; s++) {
      ah[s] = *(const v8bf*)&Asp[0][s][rdrow][0];
      al[s] = *(const v8bf*)&Asp[1][s][rdrow][0];
      a3[s] = *(const v8bf*)&Asp[2][s][rdrow][0];
    }
#pragma unroll
    for (int tau = 0; tau < 4; tau++) {
      v4f accL = {0.0f, 0.0f, 0.0f, 0.0f};   // s 0,1  (old kh=0 chain)
      v4f accH = {0.0f, 0.0f, 0.0f, 0.0f};   // s 2,3  (old kh=1 chain)
#pragma unroll
      for (int s = 0; s < 4; s++) {
        v8bf wll = *(const v8bf*)(wllbase + (s >> 1) * 32768 +
                                  (tau * 2 + (s & 1)) * 512);
        v4f acc = (s < 2) ? accL : accH;
        acc = __builtin_amdgcn_mfma_f32_16x16x32_bf16(ah[s], whi[tau][s], acc, 0, 0, 0);
        acc = __builtin_amdgcn_mfma_f32_16x16x32_bf16(ah[s], wlo[tau][s], acc, 0, 0, 0);
        acc = __builtin_amdgcn_mfma_f32_16x16x32_bf16(al[s], whi[tau][s], acc, 0, 0, 0);
        acc = __builtin_amdgcn_mfma_f32_16x16x32_bf16(al[s], wlo[tau][s], acc, 0, 0, 0);
        acc = __builtin_amdgcn_mfma_f32_16x16x32_bf16(ah[s], wll, acc, 0, 0, 0);
        acc = __builtin_amdgcn_mfma_f32_16x16x32_bf16(a3[s], whi[tau][s], acc, 0, 0, 0);
        if (s < 2) accL = acc; else accH = acc;
      }
      // D: row(m) = lq*4+reg, col(gate) = l15. Valid m<6.
      int gate = g8 * 64 + tau * 16 + l15;
      if (lq == 0) {
        float* pl = P + gate * PST7;
        float* ph = pl + 512 * PST7;
#pragma unroll
        for (int reg = 0; reg < 4; reg++) { pl[reg] = accL[reg]; ph[reg] = accH[reg]; }
      } else if (lq == 1) {
        float* pl = P + gate * PST7 + 4;
        float* ph = pl + 512 * PST7;
#pragma unroll
        for (int reg = 0; reg < 2; reg++) { pl[reg] = accL[reg]; ph[reg] = accH[reg]; }
      }
    }
    __syncthreads();

    // ---- phase 2: exact fp32 x-part + bias + activations + h-splits ----
#pragma unroll
    for (int task = 0; task < 2; task++) {
      if (task == 1 && tid >= 256) break;
      const int m = task == 0 ? mq : 4 + mq;    // 0..3 / 4..5
      const int n = p2n;
      float wb[28];
#pragma unroll
      for (int q = 0; q < 14; q++) {
        float2 v = WB2[q][n];
        wb[2 * q] = v.x;
        wb[2 * q + 1] = v.y;
      }
      const float* xm = Xb8 + (m * 41 + t) * 8;   // m,t uniform -> broadcast
      float xv[6];
#pragma unroll
      for (int f = 0; f < 6; f++) xv[f] = xm[f];
      float g4[4];
#pragma unroll
      for (int g = 0; g < 4; g++) {
        float a = wb[24 + g];
#pragma unroll
        for (int f = 0; f < 6; f++) a = fmaf(wb[g * 6 + f], xv[f], a);
        int gate = n + g * 128;
        a += P[gate * PST7 + m] + P[512 * PST7 + gate * PST7 + m];
        g4[g] = a;
      }
      float& c = task == 0 ? c0 : c1;
      c = sigm(g4[1]) * c + sigm(g4[0]) * tanhf(g4[2]);
      float h = sigm(g4[3]) * tanhf(c);
      if (t >= 30) H10[((size_t)(s0 + m) * 10 + (t - 30)) * 128 + n] = h;
      __bf16 hh = (__bf16)h;
      float r1 = h - (float)hh;
      __bf16 hl = (__bf16)r1;
      float r2 = r1 - (float)hl;
      __bf16 h3 = (__bf16)r2;
      int g = (n >> 3) & 3;
      int ks = n >> 5;
      int j = n & 7;
      int row = 16 * g + ((m + 2 * g) & 15);   // bank-spreading row perm
      Asp[0][ks][row][j] = hh;
      Asp[1][ks][row][j] = hl;
      Asp[2][ks][row][j] = h3;
    }
    __syncthreads();
  }
}

// ---------------------------------------------------------------------------
// Kernel 2: fused K+Q projection. Out[r] = l2norm(LN(In_row[r]) @ W^T).
// Blocks [0,1875) = K path; [1875,2063) = Q path (+ linear bf16 hi/lo split).
// LN fused into the tile load (bit-identical wave-butterfly).
// ---------------------------------------------------------------------------
__global__ __launch_bounds__(256) void proj_kernel(
    const float* __restrict__ In, const float* __restrict__ WK,
    const float* __restrict__ WQ, const float* __restrict__ lng,
    const float* __restrict__ lnb, float* __restrict__ Kn,
    float* __restrict__ Qn, unsigned short* __restrict__ Qhi,
    unsigned short* __restrict__ Qlo)
{
  __shared__ float A_s[16 * 128];
  const int tid = threadIdx.x;
  const int bk = blockIdx.x;
  const bool isQ = bk >= 1875;
  const int inOff = isQ ? 9 * 128 : 0;
  const int inStride = isQ ? 1280 : 128;
  const int nr = isQ ? 3000 : 30000;
  const float* W = isQ ? WQ : WK;
  float* Out = isQ ? Qn : Kn;
  unsigned short* OutHi = isQ ? Qhi : nullptr;
  unsigned short* OutLo = isQ ? Qlo : nullptr;
  const int r0 = (isQ ? bk - 1875 : bk) * 16;

  for (int i = tid; i < 16 * 32; i += 256) {
    int row = i >> 5, c = i & 31;
    int gr = r0 + row;
    float4 v = make_float4(0.f, 0.f, 0.f, 0.f);
    if (gr < nr)
      v = *(const float4*)(In + (size_t)inOff + (size_t)gr * inStride + c * 4);
    *(float4*)(A_s + row * 128 + c * 4) = v;
  }
  __syncthreads();

  // fused LayerNorm, rows 4*wave..4*wave+3 (identical arithmetic to the old
  // ln_kernel: 64-lane butterfly, population var, eps inside sqrt)
  {
    const int wvv = tid >> 6, lane = tid & 63;
    const float g0 = lng[lane], g1 = lng[lane + 64];
    const float bb0 = lnb[lane], bb1 = lnb[lane + 64];
#pragma unroll
    for (int p = 0; p < 4; p++) {
      float* hr = A_s + (wvv * 4 + p) * 128;
      float x0 = hr[lane], x1 = hr[lane + 64];
      float s = x0 + x1;
      for (int off = 32; off > 0; off >>= 1) s += __shfl_xor(s, off);
      float mean = s * (1.0f / 128.0f);
      float d0 = x0 - mean, d1 = x1 - mean;
      float v = d0 * d0 + d1 * d1;
      for (int off = 32; off > 0; off >>= 1) v += __shfl_xor(v, off);
      float rstd = 1.0f / sqrtf(v * (1.0f / 128.0f) + 1e-5f);
      hr[lane] = d0 * rstd * g0 + bb0;
      hr[lane + 64] = d1 * rstd * g1 + bb1;
    }
  }
  __syncthreads();

  const int j = tid & 127, rh = tid >> 7;
  const float* wrow = W + j * 128;
  float acc[8] = {0, 0, 0, 0, 0, 0, 0, 0};
  for (int kc = 0; kc < 32; kc++) {
    float4 wv4 = *(const float4*)(wrow + kc * 4);
#pragma unroll
    for (int i = 0; i < 8; i++) {
      float4 a4 = *(const float4*)(A_s + (rh * 8 + i) * 128 + kc * 4);
      acc[i] = fmaf(wv4.x, a4.x, acc[i]);
      acc[i] = fmaf(wv4.y, a4.y, acc[i]);
      acc[i] = fmaf(wv4.z, a4.z, acc[i]);
      acc[i] = fmaf(wv4.w, a4.w, acc[i]);
    }
  }
  __syncthreads();
#pragma unroll
  for (int i = 0; i < 8; i++) A_s[(rh * 8 + i) * 128 + j] = acc[i];
  __syncthreads();

  const int r = tid >> 4, qq = tid & 15;
  float ss = 0.0f;
#pragma unroll
  for (int i = 0; i < 8; i++) {
    float u = A_s[r * 128 + qq + i * 16];
    ss += u * u;
  }
  for (int off = 8; off > 0; off >>= 1) ss += __shfl_xor(ss, off);
  float scale = 1.0f / fmaxf(sqrtf(ss), 1e-12f);
  int gr = r0 + r;
  if (gr < nr) {
#pragma unroll
    for (int i = 0; i < 8; i++) {
      float val = A_s[r * 128 + qq + i * 16] * scale;
      int col = qq + i * 16;
      Out[(size_t)gr * 128 + col] = val;
      if (OutHi) {   // linear bf16 hi/lo split (Q path)
        unsigned short h = f2bf_rne(val);
        unsigned short l = f2bf_rne(val - bf2f(h));
        OutHi[(size_t)gr * 128 + col] = h;
        OutLo[(size_t)gr * 128 + col] = l;
      }
    }
  }
}

// ---------------------------------------------------------------------------
// Kernel 2c-K: fp32 K -> blocked bf16 hi/lo for coalesced score loads.
// (Kept separate: Khi/Klo overlay H10, so fusing into proj would race other
// blocks' H10 reads.)
// idx = tile*4096 + s*512 + half*256 + r*8 + e; col = s*16+half*8+e, r=row%32.
// ---------------------------------------------------------------------------
__global__ __launch_bounds__(256) void cvt_blockK(
    const float* __restrict__ Kn, unsigned short* __restrict__ hi,
    unsigned short* __restrict__ lo)
{
  const int tile = blockIdx.x;
  const int tid = threadIdx.x;
#pragma unroll
  for (int jj = 0; jj < 4; jj++) {
    int i = tid + jj * 256;
    int r = i >> 5;
    int c0 = (i & 31) * 4;
    int row = tile * 32 + r;
    if (row >= NCOLS) continue;
    float4 f = *(const float4*)(Kn + (size_t)row * 128 + c0);
    ushort4 h, l;
    h.x = f2bf_rne(f.x); l.x = f2bf_rne(f.x - bf2f(h.x));
    h.y = f2bf_rne(f.y); l.y = f2bf_rne(f.y - bf2f(h.y));
    h.z = f2bf_rne(f.z); l.z = f2bf_rne(f.z - bf2f(h.z));
    h.w = f2bf_rne(f.w); l.w = f2bf_rne(f.w - bf2f(h.w));
    int s = c0 >> 4, half = (c0 >> 3) & 1, e = c0 & 7;
    size_t idx = (size_t)tile * 4096 + s * 512 + half * 256 + r * 8 + e;
    *(ushort4*)(hi + idx) = h;
    *(ushort4*)(lo + idx) = l;
  }
}

// ---------------------------------------------------------------------------
// Kernel 3: MFMA score + per-chunk approx top-8 (unchanged from R11):
// chunk == XCD (lid&7), wave-uniform lag arithmetic, range-check self-mask.
// ---------------------------------------------------------------------------
__global__ __launch_bounds__(256, 3) void score_mfma(
    const unsigned short* __restrict__ Qh, const unsigned short* __restrict__ Ql,
    const unsigned short* __restrict__ Kh, const unsigned short* __restrict__ Kl,
    const int* __restrict__ tix, const float* __restrict__ log_temp,
    const float* __restrict__ lag_bias, float* __restrict__ part)
{
  __shared__ float lagS2[42];     // lag_bias replicated: lagS2[i] = lag_bias[i%10]
  __shared__ float M[256 * 16];
  const int tid = threadIdx.x;
  const int wv = tid >> 6, lane = tid & 63;
  const int half = lane >> 5, tcol = lane & 31;

  // chunk<->XCD affinity remap: lid%8 is the HW XCD round-robin.
  const int lid = blockIdx.y * 94 + blockIdx.x;
  const int chunk = lid & 7;          // == XCD id
  const int T0 = (lid >> 3) * 32;     // 0..93 target tiles
  const int tstart = chunk * TPC;
  const int tend = (tstart + TPC < KTILES) ? tstart + TPC : KTILES;

  for (int i = tid; i < 42; i += 256) lagS2[i] = lag_bias[i % 10];

  const int tgt = T0 + tcol;
  const int tgtc = tgt < S_N ? tgt : S_N - 1;
  const int myTix = tix[tgtc];
  const int selfLo = myTix * 10;
  const float invtemp =
      1.0f / fminf(fmaxf(expf(log_temp[0]), 0.1f), 11.313708499f);

  v8bf bh[8], bl[8];
  {
    const size_t qo = (size_t)myTix * 128 + half * 8;
#pragma unroll
    for (int s = 0; s < 8; s++) {
      bh[s] = *(const v8bf*)(Qh + qo + s * 16);
      bl[s] = *(const v8bf*)(Ql + qo + s * 16);
    }
  }
#pragma unroll
  for (int s = 0; s < 8; s++) {
    asm volatile("" : "+v"(bh[s]), "+v"(bl[s]));
  }

  float tv[8]; int ti[8];
#pragma unroll
  for (int q = 0; q < 8; q++) { tv[q] = -3e38f; ti[q] = 0x7fffffff; }

  __syncthreads();

  for (int it = 0; it < 30; it++) {
    const int tile = tstart + it * 4 + wv;
    const int tilec = tile < KTILES ? tile : KTILES - 1;
    const size_t ao = (size_t)tilec * 4096 + half * 256 + tcol * 8;

    v16f acc0, acc1;
#pragma unroll
    for (int q = 0; q < 16; q++) { acc0[q] = 0.0f; acc1[q] = 0.0f; }

#pragma unroll
    for (int s = 0; s < 8; s++) {
      v8bf ah = *(const v8bf*)(Kh + ao + s * 512);
      v8bf al = *(const v8bf*)(Kl + ao + s * 512);
      acc0 = __builtin_amdgcn_mfma_f32_32x32x16_bf16(ah, bh[s], acc0, 0, 0, 0);
      acc1 = __builtin_amdgcn_mfma_f32_32x32x16_bf16(ah, bl[s], acc1, 0, 0, 0);
      acc1 = __builtin_amdgcn_mfma_f32_32x32x16_bf16(al, bh[s], acc1, 0, 0, 0);
    }

    const int cb = tile * 32;
    const int m0 = cb % 10;          // wave-uniform -> scalar div, once/tile
    const bool act = tile < tend;
#pragma unroll
    for (int reg = 0; reg < 16; reg++) {
      const int row = (reg & 3) + 8 * (reg >> 2) + 4 * half;
      const int col = cb + row;
      float vsc = fmaf(acc0[reg] + acc1[reg], invtemp, lagS2[m0 + row]);
      if (act && col < NCOLS && (unsigned)(col - selfLo) >= 10u)
        insS<8>(tv, ti, vsc, col);
    }
  }

  {
    float* my = M + tid * 16;
#pragma unroll
    for (int q = 0; q < 8; q++) {
      my[2 * q] = tv[q];
      my[2 * q + 1] = __int_as_float(ti[q]);
    }
  }
  __syncthreads();
  if (tid < 32 && T0 + tid < S_N) {
    float v[8]; int ix[8];
#pragma unroll
    for (int q = 0; q < 8; q++) { v[q] = -3e38f; ix[q] = 0x7fffffff; }
    for (int w = 0; w < 8; w++) {
      const float* src = M + (w * 32 + tid) * 16;
#pragma unroll
      for (int q = 0; q < 8; q++)
        insF<8>(v, ix, src[2 * q], __float_as_int(src[2 * q + 1]));
    }
    float* dst = part + ((size_t)(T0 + tid) * SCHUNK + chunk) * 16;
#pragma unroll
    for (int q = 0; q < 8; q++) {
      dst[2 * q] = v[q];
      dst[2 * q + 1] = __int_as_float(ix[q]);
    }
  }
}

// ---------------------------------------------------------------------------
// Kernel 4: merge chunks -> approx top-8, exact fp32 rescore -> exact top-5,
// softmax, gather z, MLP (unchanged).
// ---------------------------------------------------------------------------
__global__ __launch_bounds__(256) void final_kernel(
    const float* __restrict__ part, const float* __restrict__ Qn,
    const float* __restrict__ Kn, const int* __restrict__ tix,
    const float* __restrict__ log_temp, const float* __restrict__ lag_bias,
    const float* __restrict__ Xraw,
    const float* __restrict__ W1, const float* __restrict__ b1,
    const float* __restrict__ W2, const float* __restrict__ b2,
    const float* __restrict__ W3, const float* __restrict__ b3,
    float* __restrict__ out)
{
  __shared__ float W1s[64 * 12];
  __shared__ float W2s[32 * 64];
  __shared__ float b1s[64];
  __shared__ float b2s[32];
  __shared__ float W3s[32];
  const int tid = threadIdx.x;
  for (int i = tid; i < 768; i += 256) W1s[i] = W1[i];
  for (int i = tid; i < 2048; i += 256) W2s[i] = W2[i];
  if (tid < 64) b1s[tid] = b1[tid];
  if (tid < 32) { b2s[tid] = b2[tid]; W3s[tid] = W3[tid]; }
  __syncthreads();

  int t = blockIdx.x * 256 + tid;
  if (t >= S_N) return;

  float av[8]; int ai[8];
#pragma unroll
  for (int q = 0; q < 8; q++) { av[q] = -3e38f; ai[q] = 0x7fffffff; }
  const float* pp = part + (size_t)t * (SCHUNK * 16);
  for (int c = 0; c < SCHUNK * 8; c++)
    insF<8>(av, ai, pp[2 * c], __float_as_int(pp[2 * c + 1]));

  const float invtemp =
      1.0f / fminf(fmaxf(expf(log_temp[0]), 0.1f), 11.313708499f);
  const float* q = Qn + (size_t)tix[t] * 128;
  const float* kr[8];
#pragma unroll
  for (int j = 0; j < 8; j++) kr[j] = Kn + (size_t)ai[j] * 128;
  float d[8] = {0, 0, 0, 0, 0, 0, 0, 0};
  for (int kc = 0; kc < 32; kc++) {
    float4 q4 = ((const float4*)q)[kc];
#pragma unroll
    for (int j = 0; j < 8; j++) {
      float4 k4 = ((const float4*)kr[j])[kc];
      d[j] = fmaf(q4.x, k4.x, d[j]);
      d[j] = fmaf(q4.y, k4.y, d[j]);
      d[j] = fmaf(q4.z, k4.z, d[j]);
      d[j] = fmaf(q4.w, k4.w, d[j]);
    }
  }

  float v[5]; int ix[5];
#pragma unroll
  for (int qq = 0; qq < 5; qq++) { v[qq] = -3e38f; ix[qq] = 0x7fffffff; }
#pragma unroll
  for (int j = 0; j < 8; j++) {
    int c = ai[j];
    int s = c / 10;
    int lag = c - 10 * s;
    float ev = d[j] * invtemp + lag_bias[lag];
    insF<5>(v, ix, ev, c);
  }

  float e1 = expf(v[1] - v[0]), e2 = expf(v[2] - v[0]),
        e3 = expf(v[3] - v[0]), e4 = expf(v[4] - v[0]);
  float rs = 1.0f / (1.0f + e1 + e2 + e3 + e4);
  float w_[5] = {rs, e1 * rs, e2 * rs, e3 * rs, e4 * rs};

  float feat[12];
#pragma unroll
  for (int f = 0; f < 12; f++) feat[f] = 0.0f;
#pragma unroll
  for (int qq = 0; qq < 5; qq++) {
    int iq = ix[qq];
    int s = iq / 10;
    int l = iq - 10 * s;
    int pos = 29 + l;
    const float* zp = Xraw + (size_t)s * 240 + pos * 6;
#pragma unroll
    for (int f = 0; f < 6; f++) {
      float z = zp[f];
      feat[f] += w_[qq] * z;
      if (qq == 0) feat[6 + f] = z;
    }
  }

  float h1[64];
#pragma unroll 4
  for (int o = 0; o < 64; o++) {
    float acc = b1s[o];
    const float* wr = W1s + o * 12;
#pragma unroll
    for (int f = 0; f < 12; f++) acc = fmaf(wr[f], feat[f], acc);
    h1[o] = fmaxf(acc, 0.0f);
  }
  float rr = b3[0];
#pragma unroll 2
  for (int o = 0; o < 32; o++) {
    float acc = b2s[o];
    const float* wr = W2s + o * 64;
#pragma unroll 8
    for (int k = 0; k < 64; k++) acc = fmaf(wr[k], h1[k], acc);
    rr = fmaf(W3s[o], fmaxf(acc, 0.0f), rr);
  }
  out[t] = rr;
}

// ---------------------------------------------------------------------------
extern "C" void kernel_launch(void* const* d_in, const int* in_sizes, int n_in,
                              void* d_out, int out_size, void* d_ws,
                              size_t ws_size, hipStream_t stream) {
  const float* Xs   = (const float*)d_in[0];
  const float* Xraw = (const float*)d_in[1];
  const int*   tix  = (const int*)d_in[2];
  const float* Wih  = (const float*)d_in[3];
  const float* Whh  = (const float*)d_in[4];
  const float* bih  = (const float*)d_in[5];
  const float* bhh  = (const float*)d_in[6];
  const float* ln_g = (const float*)d_in[7];
  const float* ln_b = (const float*)d_in[8];
  const float* WQ   = (const float*)d_in[9];
  const float* WK   = (const float*)d_in[10];
  const float* log_temp = (const float*)d_in[11];
  const float* lag_bias = (const float*)d_in[12];
  const float* W1 = (const float*)d_in[13];
  const float* b1 = (const float*)d_in[14];
  const float* W2 = (const float*)d_in[15];
  const float* b2 = (const float*)d_in[16];
  const float* W3 = (const float*)d_in[17];
  const float* b3 = (const float*)d_in[18];
  float* outp = (float*)d_out;

  float* ws = (float*)d_ws;
  float* H10 = ws;                                          // [0, 3.84M)
  unsigned short* Khi = (unsigned short*)ws;                // overlays H10
  unsigned short* Klo = (unsigned short*)(ws + 1922000);
  float* Kn  = ws + 3850000;
  float* Qn  = ws + 7690000;
  unsigned short* Qhi = (unsigned short*)(ws + 8074000);
  unsigned short* Qlo = (unsigned short*)(ws + 8266000);
  float* part = ws + 8458000;                               // 384000 fl used
  unsigned short* Wllf = (unsigned short*)(ws + 9226000);   // 65536 us

  cvt_wll<<<256, 256, 0, stream>>>(Whh, Wllf);
  lstm_kernel<<<500, 512, 0, stream>>>(Xs, Wih, Whh, bih, bhh, Wllf, H10);
  proj_kernel<<<2063, 256, 0, stream>>>(H10, WK, WQ, ln_g, ln_b, Kn, Qn,
                                        Qhi, Qlo);
  cvt_blockK<<<KTILES, 256, 0, stream>>>(Kn, Khi, Klo);
  {
    dim3 grid(94, SCHUNK);
    score_mfma<<<grid, 256, 0, stream>>>(Qhi, Qlo, Khi, Klo, tix, log_temp,
                                         lag_bias, part);
  }
  final_kernel<<<12, 256, 0, stream>>>(part, Qn, Kn, tix, log_temp, lag_bias,
                                       Xraw, W1, b1, W2, b2, W3, b3, outp);
}

// Round 7
// 669.982 us; speedup vs baseline: 1.9346x; 1.9346x over previous
//
#include <hip/hip_runtime.h>
#include <math.h>

#define S_N 3000
#define NCOLS 30000
#define SCHUNK 8       // one chunk per XCD -> K chunk L2-resident
#define KTILES 938     // ceil(30000/32)
#define TPC 118        // tiles per chunk (8*118 = 944 >= 938)
#define PST 17         // P row stride (floats): odd -> conflict-free

typedef __bf16 v8bf __attribute__((ext_vector_type(8)));
typedef float v16f __attribute__((ext_vector_type(16)));
typedef float v4f __attribute__((ext_vector_type(4)));

__device__ __forceinline__ float sigm(float x) { return 1.0f / (1.0f + expf(-x)); }

__device__ __forceinline__ bool bet(float av, int ai, float bv, int bi) {
  return (av > bv) || (av == bv && ai < bi);
}

// streaming insert (candidates ascending by index): strict > == lax.top_k tie rule
template <int M>
__device__ __forceinline__ void insS(float (&v)[M], int (&ix)[M], float nv, int ni) {
  if (!(nv > v[M - 1])) return;
  bool b[M];
#pragma unroll
  for (int q = 0; q < M; q++) b[q] = nv > v[q];
#pragma unroll
  for (int q = M - 1; q > 0; q--) {
    v[q]  = b[q] ? (b[q - 1] ? v[q - 1] : nv) : v[q];
    ix[q] = b[q] ? (b[q - 1] ? ix[q - 1] : ni) : ix[q];
  }
  if (b[0]) { v[0] = nv; ix[0] = ni; }
}

// full comparator insert (value desc, index asc) for arbitrary-order merges
template <int M>
__device__ __forceinline__ void insF(float (&v)[M], int (&ix)[M], float nv, int ni) {
  if (!bet(nv, ni, v[M - 1], ix[M - 1])) return;
  bool b[M];
#pragma unroll
  for (int q = 0; q < M; q++) b[q] = bet(nv, ni, v[q], ix[q]);
#pragma unroll
  for (int q = M - 1; q > 0; q--) {
    v[q]  = b[q] ? (b[q - 1] ? v[q - 1] : nv) : v[q];
    ix[q] = b[q] ? (b[q - 1] ? ix[q - 1] : ni) : ix[q];
  }
  if (b[0]) { v[0] = nv; ix[0] = ni; }
}

__device__ __forceinline__ unsigned short f2bf_rne(float f) {
  unsigned int u = __float_as_uint(f);
  unsigned int r = (u + 0x7fffu + ((u >> 16) & 1u)) >> 16;
  return (unsigned short)r;
}
__device__ __forceinline__ float bf2f(unsigned short h) {
  return __uint_as_float(((unsigned int)h) << 16);
}

// ---------------------------------------------------------------------------
// Kernel 0: Whh third-split (ll) in fragment order, streamed by lstm per t.
// idx = frag*512 + lane*8 + j; frag = w*8 + tau*2 + s (w = wave 0..15).
// ---------------------------------------------------------------------------
__global__ __launch_bounds__(256) void cvt_wll(
    const float* __restrict__ Whh, unsigned short* __restrict__ Wllf)
{
  int idx = blockIdx.x * 256 + threadIdx.x;
  if (idx >= 128 * 512) return;
  int f = idx >> 9;
  int lane = (idx >> 3) & 63;
  int j = idx & 7;
  int w = f >> 3, tau = (f >> 1) & 3, s = f & 1;
  int kh = w >> 3, g8 = w & 7;
  int gate = g8 * 64 + tau * 16 + (lane & 15);
  int k = kh * 64 + s * 32 + (lane >> 4) * 8 + j;
  float x = Whh[gate * 128 + k];
  unsigned short hi = f2bf_rne(x);
  float r1 = x - bf2f(hi);
  unsigned short lo = f2bf_rne(r1);
  float r2 = r1 - bf2f(lo);
  Wllf[idx] = f2bf_rne(r2);
}

// ---------------------------------------------------------------------------
// Kernel 1: LSTM via MFMA (bf16 x3 splits, 6 MFMAs/product, fp32-noise err).
// R16: revert to the R13-proven 250x1024 / kh-split / 1-block-per-CU
// structure (R15's 2-block full-K design spilled: 128-reg unified budget at
// 4 waves/SIMD cannot hold 128 weight regs + working set -> 2.8 GB scratch
// HBM traffic, 823us). Surgical LDS-pipe cuts only, zero new live regs:
//  (a) wb[28] hoisted ABOVE the task loop: tasks 0/1 share n -> identical
//      WB2 values, but the interleaved Asp stores made the compiler reload
//      them (alias conservatism). Halves the 4-way-conflicted WB2 b64
//      traffic for dual-task threads (-112 of 336 instr/CU/t).
//  (b) Xb -> 16B-aligned padded Xb8[12*41*8]: 6 b32 broadcasts per task ->
//      2 b128 broadcasts (passed in R14/R15; values exact copies).
// R13 Asp row-permutation write/read pair kept. Numerics: bit-identical.
// ---------------------------------------------------------------------------
__global__ __launch_bounds__(1024, 4) void lstm_kernel(
    const float* __restrict__ Xs, const float* __restrict__ Wih,
    const float* __restrict__ Whh, const float* __restrict__ bih,
    const float* __restrict__ bhh, const unsigned short* __restrict__ Wllf,
    float* __restrict__ H10)
{
  __shared__ float P[2 * 512 * PST];                  // 69.6 KB
  __shared__ __align__(16) __bf16 Asp[3][4][65][8];   // 12.2 KB, ks-padded
  __shared__ __align__(16) float Xb8[12 * 41 * 8];    // 15.7 KB, padded rows
  __shared__ float2 WB2[14][128];                     // 14 KB: packed wih+bias

  const int tid = threadIdx.x;
  const int s0 = blockIdx.x * 12;
  const int lane = tid & 63;
  const int wv = tid >> 6;
  const int kh = wv >> 3;
  const int g8 = wv & 7;
  const int l15 = lane & 15, lq = lane >> 4;

  // Xb8[(m*41 + t)*8 + f] = x[s0+m][t][f] (f<6; pad 0)
  for (int i = tid; i < 12 * 40 * 8; i += 1024) {
    int m = i / 320, r = i - m * 320, t = r >> 3, f = r & 7;
    Xb8[(m * 41 + t) * 8 + f] =
        (f < 6) ? Xs[(size_t)(s0 + m) * 240 + t * 6 + f] : 0.0f;
  }
  for (int i = tid; i < 3 * 4 * 65 * 8; i += 1024)
    ((unsigned short*)Asp)[i] = 0;   // h0 = 0 (and zero pad/unused rows)
  for (int i = tid; i < 14 * 128; i += 1024) {
    int q = i >> 7, n = i & 127;
    float vv[2];
#pragma unroll
    for (int e = 0; e < 2; e++) {
      int r = 2 * q + e;
      if (r < 24) {
        int gate = n + (r / 6) * 128;
        vv[e] = Wih[gate * 6 + r % 6];
      } else {
        int gate = n + (r - 24) * 128;
        vv[e] = bih[gate] + bhh[gate];
      }
    }
    WB2[q][n] = make_float2(vv[0], vv[1]);
  }

  // resident weight fragments hi/lo: B-layout (n=l15 -> gate, quad -> k+8*lq)
  v8bf whi[4][2], wlo[4][2];
#pragma unroll
  for (int tau = 0; tau < 4; tau++)
#pragma unroll
    for (int s = 0; s < 2; s++) {
      int gate = g8 * 64 + tau * 16 + l15;
      int k0 = kh * 64 + s * 32 + lq * 8;
      const float* wp = Whh + gate * 128 + k0;
      v8bf h8, l8;
#pragma unroll
      for (int j = 0; j < 8; j++) {
        float x = wp[j];
        __bf16 bh_ = (__bf16)x;
        float r1 = x - (float)bh_;
        __bf16 bl_ = (__bf16)r1;
        h8[j] = bh_;
        l8[j] = bl_;
      }
      whi[tau][s] = h8;
      wlo[tau][s] = l8;
    }

  const unsigned short* wllbase = Wllf + (size_t)(wv * 8) * 512 + lane * 8;

  float c0 = 0.0f, c1 = 0.0f;
  const int p2n = tid & 127;
  const int p2m = tid >> 7;   // 0..7
  // read row for fragment row `lane`: inverse of store row-permutation
  const int rdrow = (lane & 48) | ((lane + 2 * (lane >> 4)) & 15);

  __syncthreads();

#pragma unroll 1
  for (int t = 0; t < 40; t++) {
    // ---- phase 1: recurrent GEMM on MFMA ----
    v8bf ah[2], al[2], a3[2];
#pragma unroll
    for (int s = 0; s < 2; s++) {
      int ks = kh * 2 + s;
      ah[s] = *(const v8bf*)&Asp[0][ks][rdrow][0];
      al[s] = *(const v8bf*)&Asp[1][ks][rdrow][0];
      a3[s] = *(const v8bf*)&Asp[2][ks][rdrow][0];
    }
#pragma unroll
    for (int tau = 0; tau < 4; tau++) {
      v4f acc = {0.0f, 0.0f, 0.0f, 0.0f};
#pragma unroll
      for (int s = 0; s < 2; s++) {
        v8bf wll = *(const v8bf*)(wllbase + (tau * 2 + s) * 512);
        acc = __builtin_amdgcn_mfma_f32_16x16x32_bf16(ah[s], whi[tau][s], acc, 0, 0, 0);
        acc = __builtin_amdgcn_mfma_f32_16x16x32_bf16(ah[s], wlo[tau][s], acc, 0, 0, 0);
        acc = __builtin_amdgcn_mfma_f32_16x16x32_bf16(al[s], whi[tau][s], acc, 0, 0, 0);
        acc = __builtin_amdgcn_mfma_f32_16x16x32_bf16(al[s], wlo[tau][s], acc, 0, 0, 0);
        acc = __builtin_amdgcn_mfma_f32_16x16x32_bf16(ah[s], wll, acc, 0, 0, 0);
        acc = __builtin_amdgcn_mfma_f32_16x16x32_bf16(a3[s], whi[tau][s], acc, 0, 0, 0);
      }
      // D: row(m) = lq*4+reg, col(gate) = l15. Store m<12 (lq<3).
      if (lq < 3) {
        int gate = g8 * 64 + tau * 16 + l15;
        float* pp = P + kh * (512 * PST) + gate * PST + lq * 4;
#pragma unroll
        for (int reg = 0; reg < 4; reg++) pp[reg] = acc[reg];
      }
    }
    __syncthreads();

    // ---- phase 2: exact fp32 x-part + bias + activations + h-splits ----
    // wb hoisted: identical for both tasks (same n); avoids the compiler's
    // conservative re-load after the task-0 Asp stores.
    float wb[28];
#pragma unroll
    for (int q = 0; q < 14; q++) {
      float2 v = WB2[q][p2n];
      wb[2 * q] = v.x;
      wb[2 * q + 1] = v.y;
    }
#pragma unroll
    for (int task = 0; task < 2; task++) {
      if (task == 1 && tid >= 512) break;
      const int m = task == 0 ? p2m : 8 + p2m;
      const int n = p2n;
      float4 xa = *(const float4*)(Xb8 + (m * 41 + t) * 8);
      float4 xbv = *(const float4*)(Xb8 + (m * 41 + t) * 8 + 4);
      float xv[6] = {xa.x, xa.y, xa.z, xa.w, xbv.x, xbv.y};
      float g4[4];
#pragma unroll
      for (int g = 0; g < 4; g++) {
        float a = wb[24 + g];
#pragma unroll
        for (int f = 0; f < 6; f++) a = fmaf(wb[g * 6 + f], xv[f], a);
        int gate = n + g * 128;
        a += P[gate * PST + m] + P[512 * PST + gate * PST + m];
        g4[g] = a;
      }
      float& c = task == 0 ? c0 : c1;
      c = sigm(g4[1]) * c + sigm(g4[0]) * tanhf(g4[2]);
      float h = sigm(g4[3]) * tanhf(c);
      if (t >= 30) H10[((size_t)(s0 + m) * 10 + (t - 30)) * 128 + n] = h;
      __bf16 hh = (__bf16)h;
      float r1 = h - (float)hh;
      __bf16 hl = (__bf16)r1;
      float r2 = r1 - (float)hl;
      __bf16 h3 = (__bf16)r2;
      int g = (n >> 3) & 3;
      int ks = n >> 5;
      int j = n & 7;
      int row = 16 * g + ((m + 2 * g) & 15);   // bank-spreading row perm
      Asp[0][ks][row][j] = hh;
      Asp[1][ks][row][j] = hl;
      Asp[2][ks][row][j] = h3;
    }
    __syncthreads();
  }
}

// ---------------------------------------------------------------------------
// Kernel 2: fused K+Q projection. Out[r] = l2norm(LN(In_row[r]) @ W^T).
// Blocks [0,1875) = K path; [1875,2063) = Q path (+ linear bf16 hi/lo split).
// LN fused into the tile load (bit-identical wave-butterfly).
// ---------------------------------------------------------------------------
__global__ __launch_bounds__(256) void proj_kernel(
    const float* __restrict__ In, const float* __restrict__ WK,
    const float* __restrict__ WQ, const float* __restrict__ lng,
    const float* __restrict__ lnb, float* __restrict__ Kn,
    float* __restrict__ Qn, unsigned short* __restrict__ Qhi,
    unsigned short* __restrict__ Qlo)
{
  __shared__ float A_s[16 * 128];
  const int tid = threadIdx.x;
  const int bk = blockIdx.x;
  const bool isQ = bk >= 1875;
  const int inOff = isQ ? 9 * 128 : 0;
  const int inStride = isQ ? 1280 : 128;
  const int nr = isQ ? 3000 : 30000;
  const float* W = isQ ? WQ : WK;
  float* Out = isQ ? Qn : Kn;
  unsigned short* OutHi = isQ ? Qhi : nullptr;
  unsigned short* OutLo = isQ ? Qlo : nullptr;
  const int r0 = (isQ ? bk - 1875 : bk) * 16;

  for (int i = tid; i < 16 * 32; i += 256) {
    int row = i >> 5, c = i & 31;
    int gr = r0 + row;
    float4 v = make_float4(0.f, 0.f, 0.f, 0.f);
    if (gr < nr)
      v = *(const float4*)(In + (size_t)inOff + (size_t)gr * inStride + c * 4);
    *(float4*)(A_s + row * 128 + c * 4) = v;
  }
  __syncthreads();

  // fused LayerNorm, rows 4*wave..4*wave+3 (identical arithmetic to the old
  // ln_kernel: 64-lane butterfly, population var, eps inside sqrt)
  {
    const int wvv = tid >> 6, lane = tid & 63;
    const float g0 = lng[lane], g1 = lng[lane + 64];
    const float bb0 = lnb[lane], bb1 = lnb[lane + 64];
#pragma unroll
    for (int p = 0; p < 4; p++) {
      float* hr = A_s + (wvv * 4 + p) * 128;
      float x0 = hr[lane], x1 = hr[lane + 64];
      float s = x0 + x1;
      for (int off = 32; off > 0; off >>= 1) s += __shfl_xor(s, off);
      float mean = s * (1.0f / 128.0f);
      float d0 = x0 - mean, d1 = x1 - mean;
      float v = d0 * d0 + d1 * d1;
      for (int off = 32; off > 0; off >>= 1) v += __shfl_xor(v, off);
      float rstd = 1.0f / sqrtf(v * (1.0f / 128.0f) + 1e-5f);
      hr[lane] = d0 * rstd * g0 + bb0;
      hr[lane + 64] = d1 * rstd * g1 + bb1;
    }
  }
  __syncthreads();

  const int j = tid & 127, rh = tid >> 7;
  const float* wrow = W + j * 128;
  float acc[8] = {0, 0, 0, 0, 0, 0, 0, 0};
  for (int kc = 0; kc < 32; kc++) {
    float4 wv4 = *(const float4*)(wrow + kc * 4);
#pragma unroll
    for (int i = 0; i < 8; i++) {
      float4 a4 = *(const float4*)(A_s + (rh * 8 + i) * 128 + kc * 4);
      acc[i] = fmaf(wv4.x, a4.x, acc[i]);
      acc[i] = fmaf(wv4.y, a4.y, acc[i]);
      acc[i] = fmaf(wv4.z, a4.z, acc[i]);
      acc[i] = fmaf(wv4.w, a4.w, acc[i]);
    }
  }
  __syncthreads();
#pragma unroll
  for (int i = 0; i < 8; i++) A_s[(rh * 8 + i) * 128 + j] = acc[i];
  __syncthreads();

  const int r = tid >> 4, qq = tid & 15;
  float ss = 0.0f;
#pragma unroll
  for (int i = 0; i < 8; i++) {
    float u = A_s[r * 128 + qq + i * 16];
    ss += u * u;
  }
  for (int off = 8; off > 0; off >>= 1) ss += __shfl_xor(ss, off);
  float scale = 1.0f / fmaxf(sqrtf(ss), 1e-12f);
  int gr = r0 + r;
  if (gr < nr) {
#pragma unroll
    for (int i = 0; i < 8; i++) {
      float val = A_s[r * 128 + qq + i * 16] * scale;
      int col = qq + i * 16;
      Out[(size_t)gr * 128 + col] = val;
      if (OutHi) {   // linear bf16 hi/lo split (Q path)
        unsigned short h = f2bf_rne(val);
        unsigned short l = f2bf_rne(val - bf2f(h));
        OutHi[(size_t)gr * 128 + col] = h;
        OutLo[(size_t)gr * 128 + col] = l;
      }
    }
  }
}

// ---------------------------------------------------------------------------
// Kernel 2c-K: fp32 K -> blocked bf16 hi/lo for coalesced score loads.
// (Kept separate: Khi/Klo overlay H10, so fusing into proj would race other
// blocks' H10 reads.)
// idx = tile*4096 + s*512 + half*256 + r*8 + e; col = s*16+half*8+e, r=row%32.
// ---------------------------------------------------------------------------
__global__ __launch_bounds__(256) void cvt_blockK(
    const float* __restrict__ Kn, unsigned short* __restrict__ hi,
    unsigned short* __restrict__ lo)
{
  const int tile = blockIdx.x;
  const int tid = threadIdx.x;
#pragma unroll
  for (int jj = 0; jj < 4; jj++) {
    int i = tid + jj * 256;
    int r = i >> 5;
    int c0 = (i & 31) * 4;
    int row = tile * 32 + r;
    if (row >= NCOLS) continue;
    float4 f = *(const float4*)(Kn + (size_t)row * 128 + c0);
    ushort4 h, l;
    h.x = f2bf_rne(f.x); l.x = f2bf_rne(f.x - bf2f(h.x));
    h.y = f2bf_rne(f.y); l.y = f2bf_rne(f.y - bf2f(h.y));
    h.z = f2bf_rne(f.z); l.z = f2bf_rne(f.z - bf2f(h.z));
    h.w = f2bf_rne(f.w); l.w = f2bf_rne(f.w - bf2f(h.w));
    int s = c0 >> 4, half = (c0 >> 3) & 1, e = c0 & 7;
    size_t idx = (size_t)tile * 4096 + s * 512 + half * 256 + r * 8 + e;
    *(ushort4*)(hi + idx) = h;
    *(ushort4*)(lo + idx) = l;
  }
}

// ---------------------------------------------------------------------------
// Kernel 3: MFMA score + per-chunk approx top-8 (unchanged from R11):
// chunk == XCD (lid&7), wave-uniform lag arithmetic, range-check self-mask.
// ---------------------------------------------------------------------------
__global__ __launch_bounds__(256, 3) void score_mfma(
    const unsigned short* __restrict__ Qh, const unsigned short* __restrict__ Ql,
    const unsigned short* __restrict__ Kh, const unsigned short* __restrict__ Kl,
    const int* __restrict__ tix, const float* __restrict__ log_temp,
    const float* __restrict__ lag_bias, float* __restrict__ part)
{
  __shared__ float lagS2[42];     // lag_bias replicated: lagS2[i] = lag_bias[i%10]
  __shared__ float M[256 * 16];
  const int tid = threadIdx.x;
  const int wv = tid >> 6, lane = tid & 63;
  const int half = lane >> 5, tcol = lane & 31;

  // chunk<->XCD affinity remap: lid%8 is the HW XCD round-robin.
  const int lid = blockIdx.y * 94 + blockIdx.x;
  const int chunk = lid & 7;          // == XCD id
  const int T0 = (lid >> 3) * 32;     // 0..93 target tiles
  const int tstart = chunk * TPC;
  const int tend = (tstart + TPC < KTILES) ? tstart + TPC : KTILES;

  for (int i = tid; i < 42; i += 256) lagS2[i] = lag_bias[i % 10];

  const int tgt = T0 + tcol;
  const int tgtc = tgt < S_N ? tgt : S_N - 1;
  const int myTix = tix[tgtc];
  const int selfLo = myTix * 10;
  const float invtemp =
      1.0f / fminf(fmaxf(expf(log_temp[0]), 0.1f), 11.313708499f);

  v8bf bh[8], bl[8];
  {
    const size_t qo = (size_t)myTix * 128 + half * 8;
#pragma unroll
    for (int s = 0; s < 8; s++) {
      bh[s] = *(const v8bf*)(Qh + qo + s * 16);
      bl[s] = *(const v8bf*)(Ql + qo + s * 16);
    }
  }
#pragma unroll
  for (int s = 0; s < 8; s++) {
    asm volatile("" : "+v"(bh[s]), "+v"(bl[s]));
  }

  float tv[8]; int ti[8];
#pragma unroll
  for (int q = 0; q < 8; q++) { tv[q] = -3e38f; ti[q] = 0x7fffffff; }

  __syncthreads();

  for (int it = 0; it < 30; it++) {
    const int tile = tstart + it * 4 + wv;
    const int tilec = tile < KTILES ? tile : KTILES - 1;
    const size_t ao = (size_t)tilec * 4096 + half * 256 + tcol * 8;

    v16f acc0, acc1;
#pragma unroll
    for (int q = 0; q < 16; q++) { acc0[q] = 0.0f; acc1[q] = 0.0f; }

#pragma unroll
    for (int s = 0; s < 8; s++) {
      v8bf ah = *(const v8bf*)(Kh + ao + s * 512);
      v8bf al = *(const v8bf*)(Kl + ao + s * 512);
      acc0 = __builtin_amdgcn_mfma_f32_32x32x16_bf16(ah, bh[s], acc0, 0, 0, 0);
      acc1 = __builtin_amdgcn_mfma_f32_32x32x16_bf16(ah, bl[s], acc1, 0, 0, 0);
      acc1 = __builtin_amdgcn_mfma_f32_32x32x16_bf16(al, bh[s], acc1, 0, 0, 0);
    }

    const int cb = tile * 32;
    const int m0 = cb % 10;          // wave-uniform -> scalar div, once/tile
    const bool act = tile < tend;
#pragma unroll
    for (int reg = 0; reg < 16; reg++) {
      const int row = (reg & 3) + 8 * (reg >> 2) + 4 * half;
      const int col = cb + row;
      float vsc = fmaf(acc0[reg] + acc1[reg], invtemp, lagS2[m0 + row]);
      if (act && col < NCOLS && (unsigned)(col - selfLo) >= 10u)
        insS<8>(tv, ti, vsc, col);
    }
  }

  {
    float* my = M + tid * 16;
#pragma unroll
    for (int q = 0; q < 8; q++) {
      my[2 * q] = tv[q];
      my[2 * q + 1] = __int_as_float(ti[q]);
    }
  }
  __syncthreads();
  if (tid < 32 && T0 + tid < S_N) {
    float v[8]; int ix[8];
#pragma unroll
    for (int q = 0; q < 8; q++) { v[q] = -3e38f; ix[q] = 0x7fffffff; }
    for (int w = 0; w < 8; w++) {
      const float* src = M + (w * 32 + tid) * 16;
#pragma unroll
      for (int q = 0; q < 8; q++)
        insF<8>(v, ix, src[2 * q], __float_as_int(src[2 * q + 1]));
    }
    float* dst = part + ((size_t)(T0 + tid) * SCHUNK + chunk) * 16;
#pragma unroll
    for (int q = 0; q < 8; q++) {
      dst[2 * q] = v[q];
      dst[2 * q + 1] = __int_as_float(ix[q]);
    }
  }
}

// ---------------------------------------------------------------------------
// Kernel 4: merge chunks -> approx top-8, exact fp32 rescore -> exact top-5,
// softmax, gather z, MLP (unchanged).
// ---------------------------------------------------------------------------
__global__ __launch_bounds__(256) void final_kernel(
    const float* __restrict__ part, const float* __restrict__ Qn,
    const float* __restrict__ Kn, const int* __restrict__ tix,
    const float* __restrict__ log_temp, const float* __restrict__ lag_bias,
    const float* __restrict__ Xraw,
    const float* __restrict__ W1, const float* __restrict__ b1,
    const float* __restrict__ W2, const float* __restrict__ b2,
    const float* __restrict__ W3, const float* __restrict__ b3,
    float* __restrict__ out)
{
  __shared__ float W1s[64 * 12];
  __shared__ float W2s[32 * 64];
  __shared__ float b1s[64];
  __shared__ float b2s[32];
  __shared__ float W3s[32];
  const int tid = threadIdx.x;
  for (int i = tid; i < 768; i += 256) W1s[i] = W1[i];
  for (int i = tid; i < 2048; i += 256) W2s[i] = W2[i];
  if (tid < 64) b1s[tid] = b1[tid];
  if (tid < 32) { b2s[tid] = b2[tid]; W3s[tid] = W3[tid]; }
  __syncthreads();

  int t = blockIdx.x * 256 + tid;
  if (t >= S_N) return;

  float av[8]; int ai[8];
#pragma unroll
  for (int q = 0; q < 8; q++) { av[q] = -3e38f; ai[q] = 0x7fffffff; }
  const float* pp = part + (size_t)t * (SCHUNK * 16);
  for (int c = 0; c < SCHUNK * 8; c++)
    insF<8>(av, ai, pp[2 * c], __float_as_int(pp[2 * c + 1]));

  const float invtemp =
      1.0f / fminf(fmaxf(expf(log_temp[0]), 0.1f), 11.313708499f);
  const float* q = Qn + (size_t)tix[t] * 128;
  const float* kr[8];
#pragma unroll
  for (int j = 0; j < 8; j++) kr[j] = Kn + (size_t)ai[j] * 128;
  float d[8] = {0, 0, 0, 0, 0, 0, 0, 0};
  for (int kc = 0; kc < 32; kc++) {
    float4 q4 = ((const float4*)q)[kc];
#pragma unroll
    for (int j = 0; j < 8; j++) {
      float4 k4 = ((const float4*)kr[j])[kc];
      d[j] = fmaf(q4.x, k4.x, d[j]);
      d[j] = fmaf(q4.y, k4.y, d[j]);
      d[j] = fmaf(q4.z, k4.z, d[j]);
      d[j] = fmaf(q4.w, k4.w, d[j]);
    }
  }

  float v[5]; int ix[5];
#pragma unroll
  for (int qq = 0; qq < 5; qq++) { v[qq] = -3e38f; ix[qq] = 0x7fffffff; }
#pragma unroll
  for (int j = 0; j < 8; j++) {
    int c = ai[j];
    int s = c / 10;
    int lag = c - 10 * s;
    float ev = d[j] * invtemp + lag_bias[lag];
    insF<5>(v, ix, ev, c);
  }

  float e1 = expf(v[1] - v[0]), e2 = expf(v[2] - v[0]),
        e3 = expf(v[3] - v[0]), e4 = expf(v[4] - v[0]);
  float rs = 1.0f / (1.0f + e1 + e2 + e3 + e4);
  float w_[5] = {rs, e1 * rs, e2 * rs, e3 * rs, e4 * rs};

  float feat[12];
#pragma unroll
  for (int f = 0; f < 12; f++) feat[f] = 0.0f;
#pragma unroll
  for (int qq = 0; qq < 5; qq++) {
    int iq = ix[qq];
    int s = iq / 10;
    int l = iq - 10 * s;
    int pos = 29 + l;
    const float* zp = Xraw + (size_t)s * 240 + pos * 6;
#pragma unroll
    for (int f = 0; f < 6; f++) {
      float z = zp[f];
      feat[f] += w_[qq] * z;
      if (qq == 0) feat[6 + f] = z;
    }
  }

  float h1[64];
#pragma unroll 4
  for (int o = 0; o < 64; o++) {
    float acc = b1s[o];
    const float* wr = W1s + o * 12;
#pragma unroll
    for (int f = 0; f < 12; f++) acc = fmaf(wr[f], feat[f], acc);
    h1[o] = fmaxf(acc, 0.0f);
  }
  float rr = b3[0];
#pragma unroll 2
  for (int o = 0; o < 32; o++) {
    float acc = b2s[o];
    const float* wr = W2s + o * 64;
#pragma unroll 8
    for (int k = 0; k < 64; k++) acc = fmaf(wr[k], h1[k], acc);
    rr = fmaf(W3s[o], fmaxf(acc, 0.0f), rr);
  }
  out[t] = rr;
}

// ---------------------------------------------------------------------------
extern "C" void kernel_launch(void* const* d_in, const int* in_sizes, int n_in,
                              void* d_out, int out_size, void* d_ws,
                              size_t ws_size, hipStream_t stream) {
  const float* Xs   = (const float*)d_in[0];
  const float* Xraw = (const float*)d_in[1];
  const int*   tix  = (const int*)d_in[2];
  const float* Wih  = (const float*)d_in[3];
  const float* Whh  = (const float*)d_in[4];
  const float* bih  = (const float*)d_in[5];
  const float* bhh  = (const float*)d_in[6];
  const float* ln_g = (const float*)d_in[7];
  const float* ln_b = (const float*)d_in[8];
  const float* WQ   = (const float*)d_in[9];
  const float* WK   = (const float*)d_in[10];
  const float* log_temp = (const float*)d_in[11];
  const float* lag_bias = (const float*)d_in[12];
  const float* W1 = (const float*)d_in[13];
  const float* b1 = (const float*)d_in[14];
  const float* W2 = (const float*)d_in[15];
  const float* b2 = (const float*)d_in[16];
  const float* W3 = (const float*)d_in[17];
  const float* b3 = (const float*)d_in[18];
  float* outp = (float*)d_out;

  float* ws = (float*)d_ws;
  float* H10 = ws;                                          // [0, 3.84M)
  unsigned short* Khi = (unsigned short*)ws;                // overlays H10
  unsigned short* Klo = (unsigned short*)(ws + 1922000);
  float* Kn  = ws + 3850000;
  float* Qn  = ws + 7690000;
  unsigned short* Qhi = (unsigned short*)(ws + 8074000);
  unsigned short* Qlo = (unsigned short*)(ws + 8266000);
  float* part = ws + 8458000;                               // 384000 fl used
  unsigned short* Wllf = (unsigned short*)(ws + 9226000);   // 65536 us

  cvt_wll<<<256, 256, 0, stream>>>(Whh, Wllf);
  lstm_kernel<<<250, 1024, 0, stream>>>(Xs, Wih, Whh, bih, bhh, Wllf, H10);
  proj_kernel<<<2063, 256, 0, stream>>>(H10, WK, WQ, ln_g, ln_b, Kn, Qn,
                                        Qhi, Qlo);
  cvt_blockK<<<KTILES, 256, 0, stream>>>(Kn, Khi, Klo);
  {
    dim3 grid(94, SCHUNK);
    score_mfma<<<grid, 256, 0, stream>>>(Qhi, Qlo, Khi, Klo, tix, log_temp,
                                         lag_bias, part);
  }
  final_kernel<<<12, 256, 0, stream>>>(part, Qn, Kn, tix, log_temp, lag_bias,
                                       Xraw, W1, b1, W2, b2, W3, b3, outp);
}